// Round 9
// baseline (126.604 us; speedup 1.0000x reference)
//
#include <hip/hip_runtime.h>
#include <hip/hip_bf16.h>

#define N_NODES 50000
#define F_IN    512
#define HID     128
#define OUT_F   64
#define NIDX    1000
#define E_NUM   800000
#define CAP     48       // Poisson(16): P(deg>48) ~ 1e-11 per node
#define MAXFLAG 20480    // flagged-node capacity (expected ~13.6k)
#define NSCAN   196      // scan2 blocks inside the fused dispatch
#define NGBLK   1563     // gemm blocks: ceil(50000/32)

typedef __attribute__((ext_vector_type(8))) short short8;
typedef __attribute__((ext_vector_type(4))) float f32x4;

__device__ inline ushort f2bf(float f) {
    __hip_bfloat16 h = __float2bfloat16(f);   // RNE
    return *reinterpret_cast<ushort*>(&h);
}
__device__ inline float bf2f(ushort u) {
    return __uint_as_float(((uint)u) << 16);
}
__device__ inline short8 pack8(f32x4 a, f32x4 b) {
    short8 r;
    r[0] = (short)f2bf(a[0]); r[1] = (short)f2bf(a[1]);
    r[2] = (short)f2bf(a[2]); r[3] = (short)f2bf(a[3]);
    r[4] = (short)f2bf(b[0]); r[5] = (short)f2bf(b[1]);
    r[6] = (short)f2bf(b[2]); r[7] = (short)f2bf(b[3]);
    return r;
}

// async global->LDS, 16B per lane; lds ptr wave-uniform (HW adds lane*16)
#define GLOAD_LDS16(g, l) __builtin_amdgcn_global_load_lds( \
    (const __attribute__((address_space(1))) unsigned int*)(g), \
    (__attribute__((address_space(3))) unsigned int*)(l), 16, 0, 0)

// ---------------------------------------------------------------------------
// prep: W0t[n][k] = bf16(W0[k][n]) via LDS transpose; jmap[idx[j]] = j+1
// ---------------------------------------------------------------------------
__global__ __launch_bounds__(256) void prep_kernel(const float* __restrict__ W0,
                                                   ushort* __restrict__ W0t,
                                                   const int* __restrict__ idx,
                                                   ushort* __restrict__ jmap) {
    const int b = blockIdx.x;
    if (b < 64) {   // 16 k-tiles x 4 n-tiles of 32x32
        __shared__ float tl[32][33];
        const int k0 = (b & 15) * 32, n0 = (b >> 4) * 32;
        const int tx = threadIdx.x & 31, ty = threadIdx.x >> 5;   // ty 0..7
#pragma unroll
        for (int i = 0; i < 4; ++i)
            tl[ty + i * 8][tx] = W0[(size_t)(k0 + ty + i * 8) * HID + n0 + tx];
        __syncthreads();
#pragma unroll
        for (int i = 0; i < 4; ++i) {
            const int n = ty + i * 8;
            W0t[(size_t)(n0 + n) * F_IN + k0 + tx] = f2bf(tl[tx][n]);
        }
    } else {        // blocks 64..67: mark idx reps (dup winner arbitrary; output-invariant)
        const int j = (b - 64) * 256 + threadIdx.x;
        if (j < NIDX) jmap[idx[j]] = (ushort)(j + 1);
    }
}

// ---------------------------------------------------------------------------
// FUSED: blocks [0,NSCAN) = scan2 (flagged-dst edges -> bktB), 1 wave each;
//        blocks [NSCAN,NSCAN+NGBLK) = GEMM1, ONE WAVE PER BLOCK, 32 rows:
// XW0b = bf16(x @ W0). A: 2x4KB LDS dbuf via global_load_lds (fp32, swizzled
// source + swizzled read, cvt on read); B: register loads from L2-resident
// W0t, fenced by the counted-vmcnt asm (anti-sink). NO barriers in the loop.
// Occupancy does the latency hiding: ~6 resident waves/CU x ~12KB in flight.
// ---------------------------------------------------------------------------
__global__ __launch_bounds__(64, 3) void fused_gemm_scan2(
        const float* __restrict__ x, const ushort* __restrict__ W0t,
        ushort* __restrict__ XW0b,
        const int* __restrict__ esrc, const int* __restrict__ edst,
        const float* __restrict__ ew, const ushort* __restrict__ flags,
        int* __restrict__ countsB, int2* __restrict__ bktB) {
    __shared__ __align__(16) char smem[8704];   // A0|A1 (2x4KB); epilogue [16][136] f32

    if (blockIdx.x < NSCAN) {
        // ---- scan2: 196 waves grid-striding 200k edge-quads ----
        for (int q = blockIdx.x * 64 + threadIdx.x; q < E_NUM / 4; q += NSCAN * 64) {
            const int e0 = q * 4;
            const int4   d4 = *(const int4*)(edst + e0);
            const int4   s4 = *(const int4*)(esrc + e0);
            const float4 w4 = *(const float4*)(ew + e0);
#define DOIT(DD, SS, WW) { const int s = flags[DD]; if (s) { \
        const int c = atomicAdd(&countsB[s - 1], 1); \
        if (c < CAP) bktB[(size_t)(s - 1) * CAP + c] = make_int2(SS, __float_as_int(WW)); } }
            DOIT(d4.x, s4.x, w4.x) DOIT(d4.y, s4.y, w4.y)
            DOIT(d4.z, s4.z, w4.z) DOIT(d4.w, s4.w, w4.w)
#undef DOIT
        }
        return;
    }

    // ---- gemm: wave-owned 32 rows x 128 cols x K=512 ----
    const int lane = threadIdx.x;               // 0..63
    const int lr = lane & 15, lk = lane >> 4;
    const int m0 = (blockIdx.x - NSCAN) * 32;

    f32x4 acc[2][8] = {};

    auto stage = [&](int buf, int kt) {         // A tile: 32 rows x 32 f32 = 4KB
#pragma unroll
        for (int j = 0; j < 4; ++j) {
            const int c = j * 64 + lane;        // 16B chunk id (8 chunks/row)
            const int r = c >> 3;
            int grow = m0 + r; if (grow > N_NODES - 1) grow = N_NODES - 1;
            const float* g = x + (size_t)grow * F_IN + kt * 32 + (((c & 7) ^ (r & 7)) << 2);
            GLOAD_LDS16(g, smem + buf * 4096 + j * 1024);
        }
    };

    stage(0, 0);
    stage(1, 1);                                // 8 loads outstanding
    const ushort* wbase = W0t + (size_t)lr * F_IN + lk * 8;
#pragma unroll
    for (int kt = 0; kt < 16; ++kt) {
        short8 b[8];
#pragma unroll
        for (int ni = 0; ni < 8; ++ni)          // 8 independent 16B L2 loads
            b[ni] = *(const short8*)(wbase + (size_t)ni * 16 * F_IN + kt * 32);
        // fence: pins all b-loads ABOVE (anti-sink) + waits A(kt) deposited.
        // outstanding here = A(kt+1)[4] + B(kt)[8] (+A(kt) if not landed)
        if (kt < 15) asm volatile("s_waitcnt vmcnt(12)" ::: "memory");
        else         asm volatile("s_waitcnt vmcnt(8)" ::: "memory");

        const char* Ab = smem + (kt & 1) * 4096;
        const int ch0 = (((2 * lk) ^ (lr & 7)) << 4);
        const int ch1 = (((2 * lk + 1) ^ (lr & 7)) << 4);
        const f32x4 lo0 = *(const f32x4*)(Ab + lr * 128 + ch0);
        const f32x4 hi0 = *(const f32x4*)(Ab + lr * 128 + ch1);
        const f32x4 lo1 = *(const f32x4*)(Ab + (16 + lr) * 128 + ch0);
        const f32x4 hi1 = *(const f32x4*)(Ab + (16 + lr) * 128 + ch1);
        const short8 a0 = pack8(lo0, hi0);      // compiler inserts lgkmcnt waits
        const short8 a1 = pack8(lo1, hi1);

        if (kt < 14) stage(kt & 1, kt + 2);     // restage freed buffer (after reads)

#pragma unroll
        for (int ni = 0; ni < 8; ++ni) {
            acc[0][ni] = __builtin_amdgcn_mfma_f32_16x16x32_bf16(a0, b[ni], acc[0][ni], 0, 0, 0);
            acc[1][ni] = __builtin_amdgcn_mfma_f32_16x16x32_bf16(a1, b[ni], acc[1][ni], 0, 0, 0);
        }
    }
    __syncthreads();   // single wave: just drains counters before LDS reuse

    // epilogue: acc (col=lr, row=lk*4+r) -> LDS transpose -> coalesced 16B stores
    float* ep = (float*)smem;                   // [16][136] f32
#pragma unroll
    for (int mi = 0; mi < 2; ++mi) {
        __syncthreads();
#pragma unroll
        for (int ni = 0; ni < 8; ++ni)
#pragma unroll
            for (int r = 0; r < 4; ++r)
                ep[(lk * 4 + r) * 136 + ni * 16 + lr] = acc[mi][ni][r];
        __syncthreads();
        const int rr = lane >> 2, cg = lane & 3;   // row 0..15, 32-col group
        const int grow = m0 + mi * 16 + rr;
        alignas(16) float vv[32];
#pragma unroll
        for (int j = 0; j < 8; ++j)
            *(f32x4*)&vv[j * 4] = *(const f32x4*)&ep[rr * 136 + cg * 32 + j * 4];
        if (grow < N_NODES) {
            alignas(16) ushort us[32];
#pragma unroll
            for (int jj = 0; jj < 32; ++jj) us[jj] = f2bf(vv[jj]);
            ushort* orow = XW0b + (size_t)grow * HID + cg * 32;
#pragma unroll
            for (int k = 0; k < 4; ++k)
                *(uint4*)(orow + k * 8) = *(const uint4*)&us[k * 8];
        }
    }
}

// ---------------------------------------------------------------------------
// scan 1 (4 edges/thread, streamed esrc/ew): idx-dst edges -> bktA + flag srcs
// ---------------------------------------------------------------------------
__global__ __launch_bounds__(256) void bucket_idx_kernel(const int* __restrict__ esrc,
                                                         const int* __restrict__ edst,
                                                         const float* __restrict__ ew,
                                                         const ushort* __restrict__ jmap,
                                                         int* __restrict__ countsA,
                                                         int2* __restrict__ bktA,
                                                         ushort* __restrict__ flags) {
    const int e0 = (blockIdx.x * 256 + threadIdx.x) * 4;
    if (e0 >= E_NUM) return;
    const int4   d4 = *(const int4*)(edst + e0);
    const int4   s4 = *(const int4*)(esrc + e0);
    const float4 w4 = *(const float4*)(ew + e0);
#define DOIT(DD, SS, WW) { const int rep = jmap[DD]; if (rep) { \
        const int r = rep - 1; const int c = atomicAdd(&countsA[r], 1); \
        if (c < CAP) bktA[(size_t)r * CAP + c] = make_int2(SS, __float_as_int(WW)); \
        flags[SS] = 1; } }
    DOIT(d4.x, s4.x, w4.x) DOIT(d4.y, s4.y, w4.y)
    DOIT(d4.z, s4.z, w4.z) DOIT(d4.w, s4.w, w4.w)
#undef DOIT
}

__global__ __launch_bounds__(256) void compact_kernel(ushort* __restrict__ flags,
                                                      int* __restrict__ list,
                                                      int* __restrict__ nflag) {
    const int n = blockIdx.x * 256 + threadIdx.x;
    if (n < N_NODES && flags[n]) {
        const int s = atomicAdd(nflag, 1);
        if (s < MAXFLAG) { flags[n] = (ushort)(s + 1); list[s] = n; }
        else flags[n] = 0;
    }
}

// ---------------------------------------------------------------------------
// SPMM1+ReLU over compacted flagged nodes; 1 wave/node, 2 cols/lane, unroll-4
// ---------------------------------------------------------------------------
__global__ __launch_bounds__(256) void spmm1_kernel(const ushort* __restrict__ XW0b,
                                                    const int* __restrict__ list,
                                                    const int* __restrict__ nflag,
                                                    const int* __restrict__ countsB,
                                                    const int2* __restrict__ bktB,
                                                    ushort* __restrict__ H) {
    const int lane = threadIdx.x & 63;
    const int nf = *nflag;
    const int nw = gridDim.x * 4;
    for (int wdx = blockIdx.x * 4 + (threadIdx.x >> 6); wdx < nf; wdx += nw) {
        const int n = list[wdx];
        const int deg = min(countsB[wdx], CAP);
        float a0 = 0.f, a1 = 0.f;
        int c = 0;
        for (; c + 3 < deg; c += 4) {             // 4 gathers in flight
            const int2 p0 = bktB[(size_t)wdx * CAP + c];
            const int2 p1 = bktB[(size_t)wdx * CAP + c + 1];
            const int2 p2 = bktB[(size_t)wdx * CAP + c + 2];
            const int2 p3 = bktB[(size_t)wdx * CAP + c + 3];
            const uint v0 = *(const uint*)(XW0b + (size_t)p0.x * HID + 2 * lane);
            const uint v1 = *(const uint*)(XW0b + (size_t)p1.x * HID + 2 * lane);
            const uint v2 = *(const uint*)(XW0b + (size_t)p2.x * HID + 2 * lane);
            const uint v3 = *(const uint*)(XW0b + (size_t)p3.x * HID + 2 * lane);
            const float w0 = __int_as_float(p0.y), w1 = __int_as_float(p1.y);
            const float w2 = __int_as_float(p2.y), w3 = __int_as_float(p3.y);
            a0 += w0 * bf2f((ushort)(v0 & 0xffffu)) + w1 * bf2f((ushort)(v1 & 0xffffu))
                + w2 * bf2f((ushort)(v2 & 0xffffu)) + w3 * bf2f((ushort)(v3 & 0xffffu));
            a1 += w0 * bf2f((ushort)(v0 >> 16))     + w1 * bf2f((ushort)(v1 >> 16))
                + w2 * bf2f((ushort)(v2 >> 16))     + w3 * bf2f((ushort)(v3 >> 16));
        }
        for (; c < deg; ++c) {
            const int2 p = bktB[(size_t)wdx * CAP + c];
            const float wt = __int_as_float(p.y);
            const uint v = *(const uint*)(XW0b + (size_t)p.x * HID + 2 * lane);
            a0 += wt * bf2f((ushort)(v & 0xffffu));
            a1 += wt * bf2f((ushort)(v >> 16));
        }
        const uint o = (uint)f2bf(fmaxf(a0, 0.f)) | ((uint)f2bf(fmaxf(a1, 0.f)) << 16);
        *(uint*)(H + (size_t)n * HID + 2 * lane) = o;
    }
}

// ---------------------------------------------------------------------------
// SPMM2 (idx rows) fused with GEMM2: out[j] = (sum w*H[src]) @ W1
// ---------------------------------------------------------------------------
__global__ __launch_bounds__(64) void spmm2_kernel(const ushort* __restrict__ H,
                                                   const float* __restrict__ W1,
                                                   const int* __restrict__ idx,
                                                   const ushort* __restrict__ jmap,
                                                   const int* __restrict__ countsA,
                                                   const int2* __restrict__ bktA,
                                                   float* __restrict__ outp) {
    __shared__ float aggs[HID];
    const int j = blockIdx.x, lane = threadIdx.x;
    const int r = (int)jmap[idx[j]] - 1;  // rep slot (shared by dup idx entries)
    const int deg = min(countsA[r], CAP);
    float a0 = 0.f, a1 = 0.f;
    for (int c = 0; c < deg; ++c) {
        const int2 p = bktA[(size_t)r * CAP + c];
        const float wt = __int_as_float(p.y);
        const uint v = *(const uint*)(H + (size_t)p.x * HID + 2 * lane);
        a0 += wt * bf2f((ushort)(v & 0xffffu));
        a1 += wt * bf2f((ushort)(v >> 16));
    }
    aggs[2 * lane] = a0; aggs[2 * lane + 1] = a1;
    __syncthreads();
    float s = 0.f;
#pragma unroll 8
    for (int k = 0; k < HID; ++k) s += aggs[k] * W1[k * OUT_F + lane];
    outp[(size_t)j * OUT_F + lane] = s;
}

// ---------------------------------------------------------------------------
extern "C" void kernel_launch(void* const* d_in, const int* in_sizes, int n_in,
                              void* d_out, int out_size, void* d_ws, size_t ws_size,
                              hipStream_t stream) {
    const float* x    = (const float*)d_in[0];
    const float* W0   = (const float*)d_in[1];
    const float* W1   = (const float*)d_in[2];
    const float* ew   = (const float*)d_in[3];
    const int*   esrc = (const int*)d_in[4];
    const int*   edst = (const int*)d_in[5];
    const int*   idx  = (const int*)d_in[6];
    float* outp = (float*)d_out;

    char* ws = (char*)d_ws;
    ushort* XW0b   = (ushort*)(ws);                      // 12,800,000
    ushort* H      = (ushort*)(ws + 12800000);           // 12,800,000
    ushort* W0t    = (ushort*)(ws + 25600000);           //    131,072
    int2*   bktA   = (int2*)  (ws + 25731072);           //    384,000
    int2*   bktB   = (int2*)  (ws + 26115072);           //  7,864,320
    int*    list   = (int*)   (ws + 33979392);           //     81,920
    char*   zbase  = ws + 34061312;                      // zeroed control block
    int*    countsA = (int*)   (zbase);                  //      4,096
    int*    countsB = (int*)   (zbase + 4096);           //     81,920
    ushort* flags   = (ushort*)(zbase + 86016);          //    100,352
    ushort* jmap    = (ushort*)(zbase + 186368);         //    100,352
    int*    nflag   = (int*)   (zbase + 286720);         //        256
    hipMemsetAsync(zbase, 0, 286976, stream);

    prep_kernel      <<<68, 256, 0, stream>>>(W0, W0t, idx, jmap);
    bucket_idx_kernel<<<(E_NUM / 4 + 255) / 256, 256, 0, stream>>>(esrc, edst, ew, jmap, countsA, bktA, flags);
    compact_kernel   <<<(N_NODES + 255) / 256, 256, 0, stream>>>(flags, list, nflag);
    fused_gemm_scan2 <<<NSCAN + NGBLK, 64, 0, stream>>>(
                         x, W0t, XW0b, esrc, edst, ew, flags, countsB, bktB);
    spmm1_kernel     <<<1024, 256, 0, stream>>>(XW0b, list, nflag, countsB, bktB, H);
    spmm2_kernel     <<<NIDX, 64, 0, stream>>>(H, W1, idx, jmap, countsA, bktA, outp);
}

// Round 10
// 91.743 us; speedup vs baseline: 1.3800x; 1.3800x over previous
//
#include <hip/hip_runtime.h>
#include <hip/hip_bf16.h>

#define N_NODES 50000
#define F_IN    512
#define HID     128
#define OUT_F   64
#define NIDX    1000
#define E_NUM   800000
#define CAP     48       // Poisson(16): P(deg>48) ~ 1e-11 per node
#define MAXFLAG 20480    // flagged-node capacity (expected ~13.6k)
#define NSCAN   196      // scan2 blocks inside the fused dispatch
#define NGBLK   782      // gemm blocks: ceil(50000/64)

typedef __attribute__((ext_vector_type(8))) short short8;
typedef __attribute__((ext_vector_type(4))) float f32x4;

__device__ inline ushort f2bf(float f) {
    __hip_bfloat16 h = __float2bfloat16(f);   // RNE
    return *reinterpret_cast<ushort*>(&h);
}
__device__ inline float bf2f(ushort u) {
    return __uint_as_float(((uint)u) << 16);
}
__device__ inline short8 pack8(f32x4 a, f32x4 b) {
    short8 r;
    r[0] = (short)f2bf(a[0]); r[1] = (short)f2bf(a[1]);
    r[2] = (short)f2bf(a[2]); r[3] = (short)f2bf(a[3]);
    r[4] = (short)f2bf(b[0]); r[5] = (short)f2bf(b[1]);
    r[6] = (short)f2bf(b[2]); r[7] = (short)f2bf(b[3]);
    return r;
}

// async global->LDS, 16B per lane; lds ptr wave-uniform (HW adds lane*16)
#define GLOAD_LDS16(g, l) __builtin_amdgcn_global_load_lds( \
    (const __attribute__((address_space(1))) unsigned int*)(g), \
    (__attribute__((address_space(3))) unsigned int*)(l), 16, 0, 0)

// ---------------------------------------------------------------------------
// prep: W0t[n][k] = bf16(W0[k][n]) via LDS transpose; jmap[idx[j]] = j+1
// ---------------------------------------------------------------------------
__global__ __launch_bounds__(256) void prep_kernel(const float* __restrict__ W0,
                                                   ushort* __restrict__ W0t,
                                                   const int* __restrict__ idx,
                                                   ushort* __restrict__ jmap) {
    const int b = blockIdx.x;
    if (b < 64) {   // 16 k-tiles x 4 n-tiles of 32x32
        __shared__ float tl[32][33];
        const int k0 = (b & 15) * 32, n0 = (b >> 4) * 32;
        const int tx = threadIdx.x & 31, ty = threadIdx.x >> 5;   // ty 0..7
#pragma unroll
        for (int i = 0; i < 4; ++i)
            tl[ty + i * 8][tx] = W0[(size_t)(k0 + ty + i * 8) * HID + n0 + tx];
        __syncthreads();
#pragma unroll
        for (int i = 0; i < 4; ++i) {
            const int n = ty + i * 8;
            W0t[(size_t)(n0 + n) * F_IN + k0 + tx] = f2bf(tl[tx][n]);
        }
    } else {        // blocks 64..67: mark idx reps (dup winner arbitrary; output-invariant)
        const int j = (b - 64) * 256 + threadIdx.x;
        if (j < NIDX) jmap[idx[j]] = (ushort)(j + 1);
    }
}

// ---------------------------------------------------------------------------
// FUSED: blocks [0,NSCAN) = scan2 (flagged-dst edges -> bktB);
//        blocks [NSCAN,NSCAN+NGBLK) = GEMM1, faithful m97 structure at
// m97 occupancy: BM=64, BN=128, BK=64, 4 waves 2x2 (wave tile 32x64),
// SINGLE-buffered LDS (A fp32 16KB + B bf16 16KB), global_load_lds width-16,
// plain __syncthreads 2-barrier loop, 782 blocks ~= 3.8 blocks/CU (m114
// inter-block overlap hides the barrier drain). Swizzle per rule 21:
// linear LDS dest + inverse-swizzled source + swizzled read.
// ---------------------------------------------------------------------------
__global__ __launch_bounds__(256, 5) void fused_gemm_scan2(
        const float* __restrict__ x, const ushort* __restrict__ W0t,
        ushort* __restrict__ XW0b,
        const int* __restrict__ esrc, const int* __restrict__ edst,
        const float* __restrict__ ew, const ushort* __restrict__ flags,
        int* __restrict__ countsB, int2* __restrict__ bktB) {
    __shared__ __align__(16) char smem[32768];   // A(16KB) | B(16KB); epilogue overlay

    if (blockIdx.x < NSCAN) {
        for (int q = blockIdx.x * 256 + threadIdx.x; q < E_NUM / 4; q += NSCAN * 256) {
            const int e0 = q * 4;
            const int4   d4 = *(const int4*)(edst + e0);
            const int4   s4 = *(const int4*)(esrc + e0);
            const float4 w4 = *(const float4*)(ew + e0);
#define DOIT(DD, SS, WW) { const int s = flags[DD]; if (s) { \
        const int c = atomicAdd(&countsB[s - 1], 1); \
        if (c < CAP) bktB[(size_t)(s - 1) * CAP + c] = make_int2(SS, __float_as_int(WW)); } }
            DOIT(d4.x, s4.x, w4.x) DOIT(d4.y, s4.y, w4.y)
            DOIT(d4.z, s4.z, w4.z) DOIT(d4.w, s4.w, w4.w)
#undef DOIT
        }
        return;
    }

    const int t = threadIdx.x;
    const int w = t >> 6, lane = t & 63;
    const int wr = w >> 1, wc = w & 1;
    const int lr = lane & 15, lk = lane >> 4;
    const int m0 = (blockIdx.x - NSCAN) * 64;

    char* lA = smem;            // [64 rows][256B]  (64 f32/row, 16 chunks)
    char* lB = smem + 16384;    // [128 rows][128B] (64 bf16/row, 8 chunks)
    f32x4 acc[2][4] = {};

    for (int kt = 0; kt < 8; ++kt) {
        const int k0 = kt * 64;
#pragma unroll
        for (int i = 0; i < 4; ++i) {
            const int o = i * 256 + t;
            {   // A: 64 rows x 16 chunks; source col swizzled by (row&7)<<1
                const int row = o >> 4, c = o & 15;
                int ga = m0 + row; if (ga > N_NODES - 1) ga = N_NODES - 1;
                const float* g = x + (size_t)ga * F_IN + k0 + ((c ^ ((row & 7) << 1)) << 2);
                GLOAD_LDS16(g, lA + (i * 256 + w * 64) * 16);
            }
            {   // B: 128 rows x 8 chunks; source col swizzled by row&7
                const int row = o >> 3, c = o & 7;
                const ushort* g = W0t + (size_t)row * F_IN + k0 + ((c ^ (row & 7)) << 3);
                GLOAD_LDS16(g, lB + (i * 256 + w * 64) * 16);
            }
        }
        __syncthreads();       // compiler drains vmcnt(0): tile visible (m97 pattern)

#pragma unroll
        for (int kk = 0; kk < 2; ++kk) {
            short8 a[2], b[4];
#pragma unroll
            for (int mi = 0; mi < 2; ++mi) {
                const int R = wr * 32 + mi * 16 + lr;
                const int cs = (kk * 8 + lk * 2) ^ ((R & 7) << 1);   // even; +1 stays adjacent
                const f32x4 lo = *(const f32x4*)(lA + R * 256 + (cs << 4));
                const f32x4 hi = *(const f32x4*)(lA + R * 256 + (cs << 4) + 16);
                a[mi] = pack8(lo, hi);
            }
#pragma unroll
            for (int ni = 0; ni < 4; ++ni) {
                const int Rb = wc * 64 + ni * 16 + lr;
                const int cs = (kk * 4 + lk) ^ (Rb & 7);
                b[ni] = *(const short8*)(lB + Rb * 128 + (cs << 4));
            }
#pragma unroll
            for (int mi = 0; mi < 2; ++mi)
#pragma unroll
                for (int ni = 0; ni < 4; ++ni)
                    acc[mi][ni] = __builtin_amdgcn_mfma_f32_16x16x32_bf16(
                        a[mi], b[ni], acc[mi][ni], 0, 0, 0);
        }
        __syncthreads();       // all reads done -> buffer reusable
    }

    // epilogue (R5/R6-verified): acc (col=lr, row=lk*4+r) -> LDS -> 16B stores
    float* ep = (float*)smem + w * (16 * 68);
#pragma unroll
    for (int mi = 0; mi < 2; ++mi) {
        __syncthreads();
#pragma unroll
        for (int ni = 0; ni < 4; ++ni)
#pragma unroll
            for (int r = 0; r < 4; ++r)
                ep[(lk * 4 + r) * 68 + ni * 16 + lr] = acc[mi][ni][r];
        __syncthreads();
        const int rr = lane >> 2, cq = lane & 3;
        const int grow = m0 + wr * 32 + mi * 16 + rr;
        alignas(16) float vv[16];
#pragma unroll
        for (int j = 0; j < 4; ++j)
            *(f32x4*)&vv[j * 4] = *(const f32x4*)&ep[rr * 68 + cq * 16 + j * 4];
        if (grow < N_NODES) {
            alignas(16) ushort us[16];
#pragma unroll
            for (int jj = 0; jj < 16; ++jj) us[jj] = f2bf(vv[jj]);
            ushort* orow = XW0b + (size_t)grow * HID + wc * 64 + cq * 16;
            *(uint4*)(orow)     = *(const uint4*)&us[0];
            *(uint4*)(orow + 8) = *(const uint4*)&us[8];
        }
    }
}

// ---------------------------------------------------------------------------
// scan 1 (4 edges/thread, streamed esrc/ew): idx-dst edges -> bktA + flag srcs
// ---------------------------------------------------------------------------
__global__ __launch_bounds__(256) void bucket_idx_kernel(const int* __restrict__ esrc,
                                                         const int* __restrict__ edst,
                                                         const float* __restrict__ ew,
                                                         const ushort* __restrict__ jmap,
                                                         int* __restrict__ countsA,
                                                         int2* __restrict__ bktA,
                                                         ushort* __restrict__ flags) {
    const int e0 = (blockIdx.x * 256 + threadIdx.x) * 4;
    if (e0 >= E_NUM) return;
    const int4   d4 = *(const int4*)(edst + e0);
    const int4   s4 = *(const int4*)(esrc + e0);
    const float4 w4 = *(const float4*)(ew + e0);
#define DOIT(DD, SS, WW) { const int rep = jmap[DD]; if (rep) { \
        const int r = rep - 1; const int c = atomicAdd(&countsA[r], 1); \
        if (c < CAP) bktA[(size_t)r * CAP + c] = make_int2(SS, __float_as_int(WW)); \
        flags[SS] = 1; } }
    DOIT(d4.x, s4.x, w4.x) DOIT(d4.y, s4.y, w4.y)
    DOIT(d4.z, s4.z, w4.z) DOIT(d4.w, s4.w, w4.w)
#undef DOIT
}

__global__ __launch_bounds__(256) void compact_kernel(ushort* __restrict__ flags,
                                                      int* __restrict__ list,
                                                      int* __restrict__ nflag) {
    const int n = blockIdx.x * 256 + threadIdx.x;
    if (n < N_NODES && flags[n]) {
        const int s = atomicAdd(nflag, 1);
        if (s < MAXFLAG) { flags[n] = (ushort)(s + 1); list[s] = n; }
        else flags[n] = 0;
    }
}

// ---------------------------------------------------------------------------
// SPMM1+ReLU over compacted flagged nodes; 1 wave/node, 2 cols/lane, unroll-4
// ---------------------------------------------------------------------------
__global__ __launch_bounds__(256) void spmm1_kernel(const ushort* __restrict__ XW0b,
                                                    const int* __restrict__ list,
                                                    const int* __restrict__ nflag,
                                                    const int* __restrict__ countsB,
                                                    const int2* __restrict__ bktB,
                                                    ushort* __restrict__ H) {
    const int lane = threadIdx.x & 63;
    const int nf = *nflag;
    const int nw = gridDim.x * 4;
    for (int wdx = blockIdx.x * 4 + (threadIdx.x >> 6); wdx < nf; wdx += nw) {
        const int n = list[wdx];
        const int deg = min(countsB[wdx], CAP);
        float a0 = 0.f, a1 = 0.f;
        int c = 0;
        for (; c + 3 < deg; c += 4) {             // 4 gathers in flight
            const int2 p0 = bktB[(size_t)wdx * CAP + c];
            const int2 p1 = bktB[(size_t)wdx * CAP + c + 1];
            const int2 p2 = bktB[(size_t)wdx * CAP + c + 2];
            const int2 p3 = bktB[(size_t)wdx * CAP + c + 3];
            const uint v0 = *(const uint*)(XW0b + (size_t)p0.x * HID + 2 * lane);
            const uint v1 = *(const uint*)(XW0b + (size_t)p1.x * HID + 2 * lane);
            const uint v2 = *(const uint*)(XW0b + (size_t)p2.x * HID + 2 * lane);
            const uint v3 = *(const uint*)(XW0b + (size_t)p3.x * HID + 2 * lane);
            const float w0 = __int_as_float(p0.y), w1 = __int_as_float(p1.y);
            const float w2 = __int_as_float(p2.y), w3 = __int_as_float(p3.y);
            a0 += w0 * bf2f((ushort)(v0 & 0xffffu)) + w1 * bf2f((ushort)(v1 & 0xffffu))
                + w2 * bf2f((ushort)(v2 & 0xffffu)) + w3 * bf2f((ushort)(v3 & 0xffffu));
            a1 += w0 * bf2f((ushort)(v0 >> 16))     + w1 * bf2f((ushort)(v1 >> 16))
                + w2 * bf2f((ushort)(v2 >> 16))     + w3 * bf2f((ushort)(v3 >> 16));
        }
        for (; c < deg; ++c) {
            const int2 p = bktB[(size_t)wdx * CAP + c];
            const float wt = __int_as_float(p.y);
            const uint v = *(const uint*)(XW0b + (size_t)p.x * HID + 2 * lane);
            a0 += wt * bf2f((ushort)(v & 0xffffu));
            a1 += wt * bf2f((ushort)(v >> 16));
        }
        const uint o = (uint)f2bf(fmaxf(a0, 0.f)) | ((uint)f2bf(fmaxf(a1, 0.f)) << 16);
        *(uint*)(H + (size_t)n * HID + 2 * lane) = o;
    }
}

// ---------------------------------------------------------------------------
// SPMM2 (idx rows) fused with GEMM2: out[j] = (sum w*H[src]) @ W1
// ---------------------------------------------------------------------------
__global__ __launch_bounds__(64) void spmm2_kernel(const ushort* __restrict__ H,
                                                   const float* __restrict__ W1,
                                                   const int* __restrict__ idx,
                                                   const ushort* __restrict__ jmap,
                                                   const int* __restrict__ countsA,
                                                   const int2* __restrict__ bktA,
                                                   float* __restrict__ outp) {
    __shared__ float aggs[HID];
    const int j = blockIdx.x, lane = threadIdx.x;
    const int r = (int)jmap[idx[j]] - 1;  // rep slot (shared by dup idx entries)
    const int deg = min(countsA[r], CAP);
    float a0 = 0.f, a1 = 0.f;
    for (int c = 0; c < deg; ++c) {
        const int2 p = bktA[(size_t)r * CAP + c];
        const float wt = __int_as_float(p.y);
        const uint v = *(const uint*)(H + (size_t)p.x * HID + 2 * lane);
        a0 += wt * bf2f((ushort)(v & 0xffffu));
        a1 += wt * bf2f((ushort)(v >> 16));
    }
    aggs[2 * lane] = a0; aggs[2 * lane + 1] = a1;
    __syncthreads();
    float s = 0.f;
#pragma unroll 8
    for (int k = 0; k < HID; ++k) s += aggs[k] * W1[k * OUT_F + lane];
    outp[(size_t)j * OUT_F + lane] = s;
}

// ---------------------------------------------------------------------------
extern "C" void kernel_launch(void* const* d_in, const int* in_sizes, int n_in,
                              void* d_out, int out_size, void* d_ws, size_t ws_size,
                              hipStream_t stream) {
    const float* x    = (const float*)d_in[0];
    const float* W0   = (const float*)d_in[1];
    const float* W1   = (const float*)d_in[2];
    const float* ew   = (const float*)d_in[3];
    const int*   esrc = (const int*)d_in[4];
    const int*   edst = (const int*)d_in[5];
    const int*   idx  = (const int*)d_in[6];
    float* outp = (float*)d_out;

    char* ws = (char*)d_ws;
    ushort* XW0b   = (ushort*)(ws);                      // 12,800,000
    ushort* H      = (ushort*)(ws + 12800000);           // 12,800,000
    ushort* W0t    = (ushort*)(ws + 25600000);           //    131,072
    int2*   bktA   = (int2*)  (ws + 25731072);           //    384,000
    int2*   bktB   = (int2*)  (ws + 26115072);           //  7,864,320
    int*    list   = (int*)   (ws + 33979392);           //     81,920
    char*   zbase  = ws + 34061312;                      // zeroed control block
    int*    countsA = (int*)   (zbase);                  //      4,096
    int*    countsB = (int*)   (zbase + 4096);           //     81,920
    ushort* flags   = (ushort*)(zbase + 86016);          //    100,352
    ushort* jmap    = (ushort*)(zbase + 186368);         //    100,352
    int*    nflag   = (int*)   (zbase + 286720);         //        256
    hipMemsetAsync(zbase, 0, 286976, stream);

    prep_kernel      <<<68, 256, 0, stream>>>(W0, W0t, idx, jmap);
    bucket_idx_kernel<<<(E_NUM / 4 + 255) / 256, 256, 0, stream>>>(esrc, edst, ew, jmap, countsA, bktA, flags);
    compact_kernel   <<<(N_NODES + 255) / 256, 256, 0, stream>>>(flags, list, nflag);
    fused_gemm_scan2 <<<NSCAN + NGBLK, 256, 0, stream>>>(
                         x, W0t, XW0b, esrc, edst, ew, flags, countsB, bktB);
    spmm1_kernel     <<<1024, 256, 0, stream>>>(XW0b, list, nflag, countsB, bktB, H);
    spmm2_kernel     <<<NIDX, 64, 0, stream>>>(H, W1, idx, jmap, countsA, bktA, outp);
}